// Round 4
// baseline (173.208 us; speedup 1.0000x reference)
//
#include <hip/hip_runtime.h>
#include <hip/hip_bf16.h>
#include <stdint.h>

// Problem constants
#define B_ 8
#define D_ 1024
#define N_ 1024
#define INTER_ 512
#define H_ 16
#define EPS_ 1e-5f

typedef __attribute__((ext_vector_type(8))) short bf16x8;
typedef __attribute__((ext_vector_type(4))) float f32x4;
typedef __attribute__((ext_vector_type(4))) unsigned short u16x4;
typedef __attribute__((ext_vector_type(8))) unsigned short u16x8;

__device__ __forceinline__ unsigned short f2bf(float f) {
  union { float f; uint32_t u; } v; v.f = f;
  uint32_t r = (v.u + 0x7FFFu + ((v.u >> 16) & 1u)) >> 16;  // RNE
  return (unsigned short)r;
}

__device__ __forceinline__ void gload_lds16(const void* g, void* l) {
  __builtin_amdgcn_global_load_lds(
      (const __attribute__((address_space(1))) void*)g,
      (__attribute__((address_space(3))) void*)l, 16, 0, 0);
}

// ---------------- fused prep: transpose-cast v | cast weights | biases+invC
__global__ __launch_bounds__(256) void k_prep(
    const float* __restrict__ v, const float* __restrict__ Wt,
    const float* __restrict__ Wp, const float* __restrict__ Wg,
    const float* __restrict__ Ww, const float* __restrict__ bt,
    const float* __restrict__ bp, const float* __restrict__ bg,
    const float* __restrict__ mask, unsigned short* __restrict__ vT,
    unsigned short* __restrict__ Wall, unsigned short* __restrict__ Wwb,
    float* __restrict__ ball, float* __restrict__ invC) {
  const int blk = blockIdx.x, tid = threadIdx.x;
  if (blk < 2048) {
    __shared__ short T[64 * 72];
    const int b = blk >> 8, tile = blk & 255;
    const int n0 = (tile & 15) * 64, d0 = (tile >> 4) * 64;
    const float* src = v + ((size_t)b * D_ + d0) * N_ + n0;
    const int c = tid & 15, rg = tid >> 4;
#pragma unroll
    for (int i = 0; i < 4; ++i) {
      const int r = rg * 4 + i;
      float4 f = *(const float4*)(src + (size_t)r * N_ + c * 4);
      const int nl = c * 4;
      T[(nl + 0) * 72 + r] = f2bf(f.x);
      T[(nl + 1) * 72 + r] = f2bf(f.y);
      T[(nl + 2) * 72 + r] = f2bf(f.z);
      T[(nl + 3) * 72 + r] = f2bf(f.w);
    }
    __syncthreads();
    unsigned short* dst = vT + ((size_t)b * N_ + n0) * D_ + d0;
    const int ch = tid & 7, nr = tid >> 3;
#pragma unroll
    for (int jj = 0; jj < 2; ++jj) {
      const int nl = nr + jj * 32;
      u16x8 val = *(const u16x8*)&T[nl * 72 + ch * 8];
      *(u16x8*)(dst + (size_t)nl * D_ + ch * 8) = val;
    }
  } else if (blk < 4096) {
    const int idx4 = (blk - 2048) * 256 + tid;
    const int total1 = 1536 * 1024 / 4;
    if (idx4 < total1) {
      const int idx = idx4 * 4;
      const int row = idx >> 10, c = idx & 1023;
      const float* src = row < 512    ? Wt + row * 1024 + c
                         : row < 1024 ? Wp + (row - 512) * 1024 + c
                                      : Wg + (row - 1024) * 1024 + c;
      float4 f = *(const float4*)src;
      u16x4 o = {f2bf(f.x), f2bf(f.y), f2bf(f.z), f2bf(f.w)};
      *(u16x4*)(Wall + idx) = o;
    } else {
      const int idx = (idx4 - total1) * 4;
      float4 f = *(const float4*)(Ww + idx);
      u16x4 o = {f2bf(f.x), f2bf(f.y), f2bf(f.z), f2bf(f.w)};
      *(u16x4*)(Wwb + idx) = o;
    }
  } else if (blk == 4096) {
    for (int i = tid; i < 512; i += 256) {
      ball[i] = bt[i]; ball[512 + i] = bp[i]; ball[1024 + i] = bg[i];
    }
  } else {
    const int b = blk - 4097;
    float s = 0.f;
    for (int i = tid; i < 1024; i += 256) s += mask[b * 1024 + i];
    for (int off = 32; off; off >>= 1) s += __shfl_down(s, off, 64);
    __shared__ float red[4];
    if ((tid & 63) == 0) red[tid >> 6] = s;
    __syncthreads();
    if (tid == 0) invC[b] = 1.0f / (red[0] + red[1] + red[2] + red[3]);
  }
}

// ---------------- GEMM-A: 256x256 tiles, BK=64, 8 waves, phase-split -------
// flat block id: b = id&7 (XCD-local batch), tile = id>>3: mt = tile%6, nt=tile/6
// mt 0..1: theta rows mt*256, epilogue -> thT (b,n,i) via LDS transpose
// mt 2..5: rg=mt-2; rows = [phi 512+rg*128 .. +128 ; g 1024+rg*128 .. +128]
//          epilogue -> bias(+mask on g) -> LDS -> S-partial MFMA -> Spart f32
__global__ __launch_bounds__(512, 2) void k_gemmA(
    const unsigned short* __restrict__ Wall, const unsigned short* __restrict__ vT,
    const float* __restrict__ ball, const float* __restrict__ mask,
    unsigned short* __restrict__ thT, float* __restrict__ Spart) {
  __shared__ __align__(16) char smem[135168];  // 2 bufs (A32K+B32K) / epilogue
  const int flat = blockIdx.x;
  const int b = flat & 7;
  const int tile = flat >> 3;
  const int mt = tile % 6, nt = tile / 6;
  const bool is_theta = (mt < 2);
  const int rg = mt - 2;

  const int tid = threadIdx.x, lane = tid & 63, w = tid >> 6;
  const int wm = w >> 2, wn = w & 3;  // 2 x 4 wave grid; wave C = 128x64

  const unsigned short* Abase;
  if (is_theta)
    Abase = Wall + (size_t)(mt * 256) * 1024;
  else
    Abase = (w < 4) ? Wall + (size_t)(512 + rg * 128) * 1024
                    : Wall + (size_t)(896 + rg * 128) * 1024;  // +r (r>=128)
  const unsigned short* Bbase = vT + ((size_t)b * N_ + nt * 256) * 1024;

  const int srow = w * 32 + (lane >> 3);  // staged row for issue i: +i*8
  const int sgl = lane & 7;

  f32x4 acc[8][4] = {};
  int cur = 0;

  // prologue: stage tile 0 into buf0
#pragma unroll
  for (int i = 0; i < 4; ++i) {
    const int r = srow + i * 8;
    const int gs = sgl ^ (r & 7);
    gload_lds16(Abase + (size_t)r * 1024 + gs * 8, smem + w * 4096 + i * 1024);
    gload_lds16(Bbase + (size_t)r * 1024 + gs * 8,
                smem + 32768 + w * 4096 + i * 1024);
  }
  __syncthreads();

  for (int t = 0; t < 16; ++t) {
    // stage t+1 into the other buffer (lands during this tile's 4 phases)
    if (t < 15) {
      const char* Asrc = (const char*)(Abase + (size_t)(t + 1) * 64);
      const char* Bsrc = (const char*)(Bbase + (size_t)(t + 1) * 64);
      char* dstA = smem + (cur ^ 1) * 65536;
      char* dstB = dstA + 32768;
#pragma unroll
      for (int i = 0; i < 4; ++i) {
        const int r = srow + i * 8;
        const int gs = sgl ^ (r & 7);
        gload_lds16(Asrc + (size_t)r * 2048 + gs * 16, dstA + w * 4096 + i * 1024);
        gload_lds16(Bsrc + (size_t)r * 2048 + gs * 16, dstB + w * 4096 + i * 1024);
      }
    }
    const char* bufA = smem + cur * 65536;
    const char* bufB = bufA + 32768;

    bf16x8 af[8];
#pragma unroll
    for (int kk = 0; kk < 2; ++kk) {
      // ---- phase (kk,0): A-frags(kk) + B nf0,1 ----
#pragma unroll
      for (int mf = 0; mf < 8; ++mf) {
        const int r = wm * 128 + mf * 16 + (lane & 15);
        int byte = r * 128 + kk * 64 + ((lane >> 4) * 16);
        byte ^= (r & 7) << 4;
        af[mf] = *(const bf16x8*)(bufA + byte);
      }
      bf16x8 b0, b1;
      {
        const int r0 = wn * 64 + 0 * 16 + (lane & 15);
        int byte0 = r0 * 128 + kk * 64 + ((lane >> 4) * 16);
        byte0 ^= (r0 & 7) << 4;
        b0 = *(const bf16x8*)(bufB + byte0);
        const int r1 = wn * 64 + 1 * 16 + (lane & 15);
        int byte1 = r1 * 128 + kk * 64 + ((lane >> 4) * 16);
        byte1 ^= (r1 & 7) << 4;
        b1 = *(const bf16x8*)(bufB + byte1);
      }
      __builtin_amdgcn_s_setprio(1);
#pragma unroll
      for (int mf = 0; mf < 8; ++mf) {
        acc[mf][0] = __builtin_amdgcn_mfma_f32_16x16x32_bf16(af[mf], b0,
                                                             acc[mf][0], 0, 0, 0);
        acc[mf][1] = __builtin_amdgcn_mfma_f32_16x16x32_bf16(af[mf], b1,
                                                             acc[mf][1], 0, 0, 0);
      }
      __builtin_amdgcn_s_setprio(0);
      __builtin_amdgcn_s_barrier();
      // ---- phase (kk,1): B nf2,3 (A reused) ----
      {
        const int r0 = wn * 64 + 2 * 16 + (lane & 15);
        int byte0 = r0 * 128 + kk * 64 + ((lane >> 4) * 16);
        byte0 ^= (r0 & 7) << 4;
        b0 = *(const bf16x8*)(bufB + byte0);
        const int r1 = wn * 64 + 3 * 16 + (lane & 15);
        int byte1 = r1 * 128 + kk * 64 + ((lane >> 4) * 16);
        byte1 ^= (r1 & 7) << 4;
        b1 = *(const bf16x8*)(bufB + byte1);
      }
      __builtin_amdgcn_s_setprio(1);
#pragma unroll
      for (int mf = 0; mf < 8; ++mf) {
        acc[mf][2] = __builtin_amdgcn_mfma_f32_16x16x32_bf16(af[mf], b0,
                                                             acc[mf][2], 0, 0, 0);
        acc[mf][3] = __builtin_amdgcn_mfma_f32_16x16x32_bf16(af[mf], b1,
                                                             acc[mf][3], 0, 0, 0);
      }
      __builtin_amdgcn_s_setprio(0);
      if (kk == 0) __builtin_amdgcn_s_barrier();
    }
    __syncthreads();  // drains vmcnt: t+1 landed; all reads of buf[cur] done
    cur ^= 1;
  }

  short* Tc = (short*)smem;  // epilogue staging, pitch 264 shorts (528 B)
  if (is_theta) {
    // stage transposed: Tc[n_l 0..255][o_l 0..255]
#pragma unroll
    for (int mf = 0; mf < 8; ++mf)
#pragma unroll
      for (int nf = 0; nf < 4; ++nf) {
        const int nl = wn * 64 + nf * 16 + (lane & 15);
        const int ol0 = wm * 128 + mf * 16 + ((lane >> 4) << 2);
        u16x4 o;
#pragma unroll
        for (int r = 0; r < 4; ++r)
          o[r] = f2bf(acc[mf][nf][r] + ball[mt * 256 + ol0 + r]);
        *(u16x4*)&Tc[nl * 264 + ol0] = o;
      }
    __syncthreads();
    const int ch = tid & 31, nr = tid >> 5;  // 32 chunks x 16 rows/pass
#pragma unroll
    for (int j = 0; j < 16; ++j) {
      const int row = nr + j * 16;
      u16x8 val = *(const u16x8*)&Tc[row * 264 + ch * 8];
      *(u16x8*)(thT + ((size_t)b * N_ + nt * 256 + row) * 512 + mt * 256 +
                ch * 8) = val;
    }
    return;
  }

  // ---- phi/g: stage rows 0-127 phi, 128-255 g (bias, mask on g) ----
#pragma unroll
  for (int mf = 0; mf < 8; ++mf)
#pragma unroll
    for (int nf = 0; nf < 4; ++nf) {
      const int nl = wn * 64 + nf * 16 + (lane & 15);
      const int ol0 = wm * 128 + mf * 16 + ((lane >> 4) << 2);
      const float mv = (wm == 1) ? mask[b * 1024 + nt * 256 + nl] : 1.0f;
      const int bb = (wm == 0) ? 512 + rg * 128 : 896 + rg * 128;  // + ol
#pragma unroll
      for (int r = 0; r < 4; ++r)
        Tc[(ol0 + r) * 264 + nl] =
            f2bf((acc[mf][nf][r] + ball[bb + ol0 + r]) * mv);
    }
  __syncthreads();

  // ---- S partials: head hl=w&3 (i = rg*128+hl*32..), n-half nh=w>>2 ----
  const int hl = w & 3, nh = w >> 2;
  f32x4 accs[2][2] = {};
#pragma unroll
  for (int ks = 0; ks < 4; ++ks) {
    const int n0 = nh * 128 + ks * 32 + ((lane >> 4) * 8);
    bf16x8 pa[2], gb[2];
#pragma unroll
    for (int mf = 0; mf < 2; ++mf) {
      const int row = hl * 32 + mf * 16 + (lane & 15);
      pa[mf] = *(const bf16x8*)&Tc[row * 264 + n0];
    }
#pragma unroll
    for (int nf = 0; nf < 2; ++nf) {
      const int row = 128 + hl * 32 + nf * 16 + (lane & 15);
      gb[nf] = *(const bf16x8*)&Tc[row * 264 + n0];
    }
#pragma unroll
    for (int mf = 0; mf < 2; ++mf)
#pragma unroll
      for (int nf = 0; nf < 2; ++nf)
        accs[mf][nf] = __builtin_amdgcn_mfma_f32_16x16x32_bf16(
            pa[mf], gb[nf], accs[mf][nf], 0, 0, 0);
  }
  __syncthreads();
  float* red = (float*)smem;  // [8][32][32] f32 = 32 KB
#pragma unroll
  for (int mf = 0; mf < 2; ++mf)
#pragma unroll
    for (int nf = 0; nf < 2; ++nf)
#pragma unroll
      for (int r = 0; r < 4; ++r)
        red[w * 1024 + (mf * 16 + (lane >> 4) * 4 + r) * 32 + nf * 16 +
            (lane & 15)] = accs[mf][nf][r];
  __syncthreads();
  for (int e = tid; e < 4096; e += 512) {
    const int h = e >> 10, idx = e & 1023;
    const float sum = red[h * 1024 + idx] + red[(h + 4) * 1024 + idx];
    Spart[(((size_t)b * 16 + rg * 4 + h) * 4 + nt) * 1024 + idx] = sum;
  }
}

// ---------------- M[b](o, h*32+d) = sum_d' Ww[o,h*32+d'] * S[b,h,d,d'] -----
__global__ __launch_bounds__(256) void k_M(const unsigned short* __restrict__ Wwb,
                                           const float* __restrict__ Spart,
                                           unsigned short* __restrict__ M) {
  const int rb = blockIdx.x, h = blockIdx.y, b = blockIdx.z;
  const int tid = threadIdx.x, lane = tid & 63, w = tid >> 6;
  __shared__ short Sb[32 * 40];
  {
    const int e0 = tid * 4;
    const float* sp = Spart + (size_t)(b * 16 + h) * 4096 + e0;
    float4 a = {0, 0, 0, 0};
#pragma unroll
    for (int s = 0; s < 4; ++s) {
      float4 p = *(const float4*)(sp + s * 1024);
      a.x += p.x; a.y += p.y; a.z += p.z; a.w += p.w;
    }
    const int row = e0 >> 5, col = e0 & 31;
    u16x4 sv = {f2bf(a.x), f2bf(a.y), f2bf(a.z), f2bf(a.w)};
    *(u16x4*)&Sb[row * 40 + col] = sv;
  }
  __syncthreads();
  const int row0w = rb * 128 + w * 32;
  f32x4 acc[2][2] = {};
  bf16x8 af[2], bfr[2];
#pragma unroll
  for (int mf = 0; mf < 2; ++mf)
    af[mf] = *(const bf16x8*)(Wwb + (size_t)(row0w + mf * 16 + (lane & 15)) * 512 +
                              h * 32 + (lane >> 4) * 8);
#pragma unroll
  for (int nf = 0; nf < 2; ++nf)
    bfr[nf] = *(const bf16x8*)&Sb[(nf * 16 + (lane & 15)) * 40 + (lane >> 4) * 8];
#pragma unroll
  for (int mf = 0; mf < 2; ++mf)
#pragma unroll
    for (int nf = 0; nf < 2; ++nf)
      acc[mf][nf] = __builtin_amdgcn_mfma_f32_16x16x32_bf16(
          af[mf], bfr[nf], acc[mf][nf], 0, 0, 0);
#pragma unroll
  for (int mf = 0; mf < 2; ++mf)
#pragma unroll
    for (int nf = 0; nf < 2; ++nf)
#pragma unroll
      for (int r = 0; r < 4; ++r) {
        const int row = row0w + mf * 16 + (lane >> 4) * 4 + r;
        const int dp = nf * 16 + (lane & 15);
        M[((size_t)b * 1024 + row) * 512 + h * 32 + dp] = f2bf(acc[mf][nf][r]);
      }
}

// ---------------- GEMM2: out = BN(M*thT^T * mask/C + bw)*mask + v ----------
#define BM 128
#define BN 128
#define BK 64

__global__ __launch_bounds__(256, 2) void k_gemm2(
    const unsigned short* __restrict__ M, const unsigned short* __restrict__ thT,
    const float* __restrict__ mask, const float* __restrict__ invC,
    const float* __restrict__ bw, const float* __restrict__ gamma,
    const float* __restrict__ beta, const float* __restrict__ mean,
    const float* __restrict__ var, const float* __restrict__ vin,
    float* __restrict__ out) {
  __shared__ __align__(16) unsigned short lA[BM * BK];
  __shared__ __align__(16) unsigned short lB[BN * BK];
  const int b = blockIdx.z, bx = blockIdx.x, by = blockIdx.y;
  const int tid = threadIdx.x, lane = tid & 63, w = tid >> 6;
  const int wr = w >> 1, wc = w & 1;

  const unsigned short* Abase = M + ((size_t)b * 1024 + by * BM) * 512;
  const unsigned short* Bbase = thT + ((size_t)b * N_ + bx * BN) * 512;

  const int srow = w * 32 + (lane >> 3);
  const int sgl = lane & 7;

  f32x4 acc[4][4] = {};

  for (int kt = 0; kt < 512 / BK; ++kt) {
#pragma unroll
    for (int i = 0; i < 4; ++i) {
      const int r = srow + i * 8;
      const int gs = sgl ^ (r & 7);
      gload_lds16(Abase + (size_t)r * 512 + kt * BK + gs * 8,
                  (char*)lA + w * 4096 + i * 1024);
      gload_lds16(Bbase + (size_t)r * 512 + kt * BK + gs * 8,
                  (char*)lB + w * 4096 + i * 1024);
    }
    __syncthreads();
#pragma unroll
    for (int kk = 0; kk < 2; ++kk) {
      bf16x8 af[4], bfr[4];
#pragma unroll
      for (int mf = 0; mf < 4; ++mf) {
        const int r = wr * 64 + mf * 16 + (lane & 15);
        int byte = r * 128 + kk * 64 + ((lane >> 4) * 16);
        byte ^= (r & 7) << 4;
        af[mf] = *(const bf16x8*)((const char*)lA + byte);
      }
#pragma unroll
      for (int nf = 0; nf < 4; ++nf) {
        const int r = wc * 64 + nf * 16 + (lane & 15);
        int byte = r * 128 + kk * 64 + ((lane >> 4) * 16);
        byte ^= (r & 7) << 4;
        bfr[nf] = *(const bf16x8*)((const char*)lB + byte);
      }
#pragma unroll
      for (int mf = 0; mf < 4; ++mf)
#pragma unroll
        for (int nf = 0; nf < 4; ++nf)
          acc[mf][nf] = __builtin_amdgcn_mfma_f32_16x16x32_bf16(
              af[mf], bfr[nf], acc[mf][nf], 0, 0, 0);
    }
    __syncthreads();
  }

  const float icb = invC[b];
#pragma unroll
  for (int mf = 0; mf < 4; ++mf) {
#pragma unroll
    for (int nf = 0; nf < 4; ++nf) {
      const int col = bx * BN + wc * 64 + nf * 16 + (lane & 15);
      const int row0 = by * BM + wr * 64 + mf * 16 + ((lane >> 4) << 2);
      const float mv = mask[b * 1024 + col];
      const float sc = mv * icb;
#pragma unroll
      for (int r = 0; r < 4; ++r) {
        const int o = row0 + r;
        float val = acc[mf][nf][r] * sc + bw[o];
        const float inv = gamma[o] * rsqrtf(var[o] + EPS_);
        val = (val - mean[o]) * inv + beta[o];
        const size_t idx = ((size_t)b * 1024 + o) * 1024 + col;
        out[idx] = val * mv + vin[idx];
      }
    }
  }
}

extern "C" void kernel_launch(void* const* d_in, const int* in_sizes, int n_in,
                              void* d_out, int out_size, void* d_ws, size_t ws_size,
                              hipStream_t stream) {
  const float* v = (const float*)d_in[0];
  const float* mask = (const float*)d_in[1];
  const float* Wg = (const float*)d_in[2];
  const float* bg = (const float*)d_in[3];
  const float* Wt = (const float*)d_in[4];
  const float* bt = (const float*)d_in[5];
  const float* Wp = (const float*)d_in[6];
  const float* bp = (const float*)d_in[7];
  const float* Ww = (const float*)d_in[8];
  const float* bw = (const float*)d_in[9];
  const float* gamma = (const float*)d_in[10];
  const float* beta = (const float*)d_in[11];
  const float* mean = (const float*)d_in[12];
  const float* var = (const float*)d_in[13];
  float* out = (float*)d_out;

  char* ws = (char*)d_ws;
  unsigned short* vT = (unsigned short*)ws;    ws += 16777216;  // (b,n,d) bf16
  unsigned short* Wall = (unsigned short*)ws;  ws += 3145728;   // (1536,1024)
  unsigned short* Wwb = (unsigned short*)ws;   ws += 1048576;   // (1024,512)
  unsigned short* thT = (unsigned short*)ws;   ws += 8388608;   // (b,n,512)
  float* Spart = (float*)ws;                   ws += 2097152;   // (b,16,4,1024) f32
  unsigned short* Mw = (unsigned short*)ws;    ws += 8388608;   // (b,1024,512)
  float* ball = (float*)ws;                    ws += 6144;      // 1536
  float* invC = (float*)ws;                    ws += 32;        // 8

  k_prep<<<4105, 256, 0, stream>>>(v, Wt, Wp, Wg, Ww, bt, bp, bg, mask,
                                   vT, Wall, Wwb, ball, invC);
  k_gemmA<<<192, 512, 0, stream>>>(Wall, vT, ball, mask, thT, Spart);
  k_M<<<dim3(8, 16, 8), 256, 0, stream>>>(Wwb, Spart, Mw);
  k_gemm2<<<dim3(8, 8, 8), 256, 0, stream>>>(Mw, thT, mask, invC, bw, gamma, beta,
                                             mean, var, v, out);
}

// Round 5
// 167.257 us; speedup vs baseline: 1.0356x; 1.0356x over previous
//
#include <hip/hip_runtime.h>
#include <hip/hip_bf16.h>
#include <stdint.h>

// Problem constants
#define B_ 8
#define D_ 1024
#define N_ 1024
#define INTER_ 512
#define H_ 16
#define EPS_ 1e-5f

typedef __attribute__((ext_vector_type(8))) short bf16x8;
typedef __attribute__((ext_vector_type(4))) float f32x4;
typedef __attribute__((ext_vector_type(4))) unsigned short u16x4;
typedef __attribute__((ext_vector_type(8))) unsigned short u16x8;

__device__ __forceinline__ unsigned short f2bf(float f) {
  union { float f; uint32_t u; } v; v.f = f;
  uint32_t r = (v.u + 0x7FFFu + ((v.u >> 16) & 1u)) >> 16;  // RNE
  return (unsigned short)r;
}

__device__ __forceinline__ void gload_lds16(const void* g, void* l) {
  __builtin_amdgcn_global_load_lds(
      (const __attribute__((address_space(1))) void*)g,
      (__attribute__((address_space(3))) void*)l, 16, 0, 0);
}

// ---------------- fused prep: transpose-cast v | cast weights | small vecs
__global__ __launch_bounds__(256) void k_prep(
    const float* __restrict__ v, const float* __restrict__ Wt,
    const float* __restrict__ Wp, const float* __restrict__ Wg,
    const float* __restrict__ Ww, const float* __restrict__ bt,
    const float* __restrict__ bp, const float* __restrict__ bg,
    const float* __restrict__ mask, const float* __restrict__ bw,
    const float* __restrict__ gamma, const float* __restrict__ beta,
    const float* __restrict__ mean, const float* __restrict__ var,
    unsigned short* __restrict__ vT, unsigned short* __restrict__ Wall,
    unsigned short* __restrict__ Wwb, float* __restrict__ ball,
    float* __restrict__ invC, float* __restrict__ bnA, float* __restrict__ bnB) {
  const int blk = blockIdx.x, tid = threadIdx.x;
  if (blk < 2048) {
    __shared__ short T[64 * 72];
    const int b = blk >> 8, tile = blk & 255;
    const int n0 = (tile & 15) * 64, d0 = (tile >> 4) * 64;
    const float* src = v + ((size_t)b * D_ + d0) * N_ + n0;
    const int c = tid & 15, rg = tid >> 4;
#pragma unroll
    for (int i = 0; i < 4; ++i) {
      const int r = rg * 4 + i;
      float4 f = *(const float4*)(src + (size_t)r * N_ + c * 4);
      const int nl = c * 4;
      T[(nl + 0) * 72 + r] = f2bf(f.x);
      T[(nl + 1) * 72 + r] = f2bf(f.y);
      T[(nl + 2) * 72 + r] = f2bf(f.z);
      T[(nl + 3) * 72 + r] = f2bf(f.w);
    }
    __syncthreads();
    unsigned short* dst = vT + ((size_t)b * N_ + n0) * D_ + d0;
    const int ch = tid & 7, nr = tid >> 3;
#pragma unroll
    for (int jj = 0; jj < 2; ++jj) {
      const int nl = nr + jj * 32;
      u16x8 val = *(const u16x8*)&T[nl * 72 + ch * 8];
      *(u16x8*)(dst + (size_t)nl * D_ + ch * 8) = val;
    }
  } else if (blk < 4096) {
    const int idx4 = (blk - 2048) * 256 + tid;
    const int total1 = 1536 * 1024 / 4;
    if (idx4 < total1) {
      const int idx = idx4 * 4;
      const int row = idx >> 10, c = idx & 1023;
      const float* src = row < 512    ? Wt + row * 1024 + c
                         : row < 1024 ? Wp + (row - 512) * 1024 + c
                                      : Wg + (row - 1024) * 1024 + c;
      float4 f = *(const float4*)src;
      u16x4 o = {f2bf(f.x), f2bf(f.y), f2bf(f.z), f2bf(f.w)};
      *(u16x4*)(Wall + idx) = o;
    } else {
      const int idx = (idx4 - total1) * 4;
      float4 f = *(const float4*)(Ww + idx);
      u16x4 o = {f2bf(f.x), f2bf(f.y), f2bf(f.z), f2bf(f.w)};
      *(u16x4*)(Wwb + idx) = o;
    }
  } else if (blk == 4096) {
    for (int i = tid; i < 512; i += 256) {
      ball[i] = bt[i]; ball[512 + i] = bp[i]; ball[1024 + i] = bg[i];
    }
    for (int i = tid; i < 1024; i += 256) {
      const float inv = gamma[i] * rsqrtf(var[i] + EPS_);
      bnA[i] = inv;
      bnB[i] = (bw[i] - mean[i]) * inv + beta[i];
    }
  } else {
    const int b = blk - 4097;
    float s = 0.f;
    for (int i = tid; i < 1024; i += 256) s += mask[b * 1024 + i];
    for (int off = 32; off; off >>= 1) s += __shfl_down(s, off, 64);
    __shared__ float red[4];
    if ((tid & 63) == 0) red[tid >> 6] = s;
    __syncthreads();
    if (tid == 0) invC[b] = 1.0f / (red[0] + red[1] + red[2] + red[3]);
  }
}

// ---------------- GEMM-A: theta -> thT | phi+g tiles -> S partials ---------
// flat grid 768: b = flat&7 (XCD-local batch), tile = flat>>3,
// by = tile>>3 (0..11), bx = tile&7 (bx fastest -> A-panel L2 reuse)
#define BM 128
#define BN 128
#define BK 64

__global__ __launch_bounds__(256, 2) void k_gemmA(
    const unsigned short* __restrict__ Wall, const unsigned short* __restrict__ vT,
    const float* __restrict__ ball, const float* __restrict__ mask,
    unsigned short* __restrict__ thT, float* __restrict__ Spart) {
  __shared__ __align__(16) short smem[128 * 132];  // 33792 B
  char* lA = (char*)smem;
  char* lB = lA + 16384;
  const int flat = blockIdx.x;
  const int b = flat & 7;
  const int tile = flat >> 3;
  const int by = tile >> 3, bx = tile & 7;
  const int tid = threadIdx.x, lane = tid & 63, w = tid >> 6;
  const int wr = w >> 1, wc = w & 1;
  const bool is_theta = (by < 4);
  const int rg = by - 4;

  const unsigned short* Abase;
  if (is_theta)
    Abase = Wall + (size_t)(by * BM) * 1024;
  else
    Abase = (w < 2) ? Wall + (size_t)(512 + rg * 64) * 1024
                    : Wall + (size_t)(1024 + rg * 64 - 64) * 1024;
  const unsigned short* Bbase = vT + ((size_t)b * N_ + bx * BN) * 1024;

  const int srow = w * 32 + (lane >> 3);
  const int sgl = lane & 7;

  f32x4 acc[4][4] = {};

  for (int kt = 0; kt < 1024 / BK; ++kt) {
#pragma unroll
    for (int i = 0; i < 4; ++i) {
      const int r = srow + i * 8;
      const int gs = sgl ^ (r & 7);
      gload_lds16(Abase + (size_t)r * 1024 + kt * BK + gs * 8,
                  lA + w * 4096 + i * 1024);
      gload_lds16(Bbase + (size_t)r * 1024 + kt * BK + gs * 8,
                  lB + w * 4096 + i * 1024);
    }
    __syncthreads();
#pragma unroll
    for (int kk = 0; kk < 2; ++kk) {
      bf16x8 af[4], bfr[4];
#pragma unroll
      for (int mf = 0; mf < 4; ++mf) {
        const int r = wr * 64 + mf * 16 + (lane & 15);
        int byte = r * 128 + kk * 64 + ((lane >> 4) * 16);
        byte ^= (r & 7) << 4;
        af[mf] = *(const bf16x8*)(lA + byte);
      }
#pragma unroll
      for (int nf = 0; nf < 4; ++nf) {
        const int r = wc * 64 + nf * 16 + (lane & 15);
        int byte = r * 128 + kk * 64 + ((lane >> 4) * 16);
        byte ^= (r & 7) << 4;
        bfr[nf] = *(const bf16x8*)(lB + byte);
      }
#pragma unroll
      for (int mf = 0; mf < 4; ++mf)
#pragma unroll
        for (int nf = 0; nf < 4; ++nf)
          acc[mf][nf] = __builtin_amdgcn_mfma_f32_16x16x32_bf16(
              af[mf], bfr[nf], acc[mf][nf], 0, 0, 0);
    }
    __syncthreads();
  }

  short* Tc = smem;  // pitch 132 shorts
  if (is_theta) {
#pragma unroll
    for (int mf = 0; mf < 4; ++mf)
#pragma unroll
      for (int nf = 0; nf < 4; ++nf) {
        const int nl = wc * 64 + nf * 16 + (lane & 15);
        const int ol0 = wr * 64 + mf * 16 + ((lane >> 4) << 2);
        u16x4 o;
#pragma unroll
        for (int r = 0; r < 4; ++r)
          o[r] = f2bf(acc[mf][nf][r] + ball[by * BM + ol0 + r]);
        *(u16x4*)&Tc[nl * 132 + ol0] = o;
      }
    __syncthreads();
    const int ch = tid & 15;
#pragma unroll
    for (int j = 0; j < 8; ++j) {
      const int row = (tid >> 4) + j * 16;
      u16x4 lo = *(const u16x4*)&Tc[row * 132 + ch * 8];
      u16x4 hi = *(const u16x4*)&Tc[row * 132 + ch * 8 + 4];
      u16x8 val = {lo[0], lo[1], lo[2], lo[3], hi[0], hi[1], hi[2], hi[3]};
      *(u16x8*)(thT + ((size_t)b * N_ + bx * BN + row) * 512 + by * BM + ch * 8) =
          val;
    }
    return;
  }

  // ---- phi/g path: stage tiles to LDS (rows 0-63 phi, 64-127 g) ----
#pragma unroll
  for (int mf = 0; mf < 4; ++mf)
#pragma unroll
    for (int nf = 0; nf < 4; ++nf) {
      const int nl = wc * 64 + nf * 16 + (lane & 15);
      const int ol0 = wr * 64 + mf * 16 + ((lane >> 4) << 2);
      const float mv = (wr == 1) ? mask[b * 1024 + bx * BN + nl] : 1.0f;
      const int gb = (wr == 0) ? 512 + rg * 64 : 1024 + rg * 64 - 64;
#pragma unroll
      for (int r = 0; r < 4; ++r)
        Tc[(ol0 + r) * 132 + nl] =
            f2bf((acc[mf][nf][r] + ball[gb + ol0 + r]) * mv);
    }
  __syncthreads();

  // ---- S partials: per head hl (0,1), wave w = n-window w*32..+32 ----
  f32x4 accs[2][2][2] = {};
#pragma unroll
  for (int hl = 0; hl < 2; ++hl) {
    bf16x8 af[2], bfr[2];
#pragma unroll
    for (int mf = 0; mf < 2; ++mf) {
      const int row = hl * 32 + mf * 16 + (lane & 15);
      af[mf] = *(const bf16x8*)&Tc[row * 132 + w * 32 + (lane >> 4) * 8];
    }
#pragma unroll
    for (int nf = 0; nf < 2; ++nf) {
      const int row = 64 + hl * 32 + nf * 16 + (lane & 15);
      bfr[nf] = *(const bf16x8*)&Tc[row * 132 + w * 32 + (lane >> 4) * 8];
    }
#pragma unroll
    for (int mf = 0; mf < 2; ++mf)
#pragma unroll
      for (int nf = 0; nf < 2; ++nf)
        accs[hl][mf][nf] = __builtin_amdgcn_mfma_f32_16x16x32_bf16(
            af[mf], bfr[nf], accs[hl][mf][nf], 0, 0, 0);
  }
  __syncthreads();
  float* red = (float*)smem;  // [2][4][32][32] = 32 KB
#pragma unroll
  for (int hl = 0; hl < 2; ++hl)
#pragma unroll
    for (int mf = 0; mf < 2; ++mf)
#pragma unroll
      for (int nf = 0; nf < 2; ++nf)
#pragma unroll
        for (int r = 0; r < 4; ++r)
          red[((hl * 4 + w) * 32 + mf * 16 + (lane >> 4) * 4 + r) * 32 +
              nf * 16 + (lane & 15)] = accs[hl][mf][nf][r];
  __syncthreads();
  for (int e = tid; e < 2048; e += 256) {
    const int hl = e >> 10, idx = e & 1023;
    const float* rb = red + (hl * 4) * 1024;
    const float sum = rb[idx] + rb[1024 + idx] + rb[2048 + idx] + rb[3072 + idx];
    const int h = rg * 2 + hl;
    Spart[(((size_t)b * 16 + h) * 8 + bx) * 1024 + idx] = sum;
  }
}

// ---------------- M[b](o, h*32+d) = sum_d' Ww[o,h*32+d'] * S[b,h,d,d'] -----
__global__ __launch_bounds__(256) void k_M(const unsigned short* __restrict__ Wwb,
                                           const float* __restrict__ Spart,
                                           unsigned short* __restrict__ M) {
  const int rb = blockIdx.x, h = blockIdx.y, b = blockIdx.z;
  const int tid = threadIdx.x, lane = tid & 63, w = tid >> 6;
  __shared__ short Sb[32 * 40];
  {
    const int e0 = tid * 4;
    const float* sp = Spart + (size_t)(b * 16 + h) * 8192 + e0;
    float4 a = {0, 0, 0, 0};
#pragma unroll
    for (int s = 0; s < 8; ++s) {
      float4 p = *(const float4*)(sp + s * 1024);
      a.x += p.x; a.y += p.y; a.z += p.z; a.w += p.w;
    }
    const int row = e0 >> 5, col = e0 & 31;
    u16x4 sv = {f2bf(a.x), f2bf(a.y), f2bf(a.z), f2bf(a.w)};
    *(u16x4*)&Sb[row * 40 + col] = sv;
  }
  __syncthreads();
  const int row0w = rb * 128 + w * 32;
  f32x4 acc[2][2] = {};
  bf16x8 af[2], bfr[2];
#pragma unroll
  for (int mf = 0; mf < 2; ++mf)
    af[mf] = *(const bf16x8*)(Wwb + (size_t)(row0w + mf * 16 + (lane & 15)) * 512 +
                              h * 32 + (lane >> 4) * 8);
#pragma unroll
  for (int nf = 0; nf < 2; ++nf)
    bfr[nf] = *(const bf16x8*)&Sb[(nf * 16 + (lane & 15)) * 40 + (lane >> 4) * 8];
#pragma unroll
  for (int mf = 0; mf < 2; ++mf)
#pragma unroll
    for (int nf = 0; nf < 2; ++nf)
      acc[mf][nf] = __builtin_amdgcn_mfma_f32_16x16x32_bf16(
          af[mf], bfr[nf], acc[mf][nf], 0, 0, 0);
#pragma unroll
  for (int mf = 0; mf < 2; ++mf)
#pragma unroll
    for (int nf = 0; nf < 2; ++nf)
#pragma unroll
      for (int r = 0; r < 4; ++r) {
        const int row = row0w + mf * 16 + (lane >> 4) * 4 + r;
        const int dp = nf * 16 + (lane & 15);
        M[((size_t)b * 1024 + row) * 512 + h * 32 + dp] = f2bf(acc[mf][nf][r]);
      }
}

// ---------------- GEMM2: out = (M*thT^T * sc)*bnA + bnB, *mask, + v --------
// flat grid 512: b = flat&7, tile = flat>>3, by = tile>>3, bx = tile&7
__global__ __launch_bounds__(256, 2) void k_gemm2(
    const unsigned short* __restrict__ M, const unsigned short* __restrict__ thT,
    const float* __restrict__ mask, const float* __restrict__ invC,
    const float* __restrict__ bnA, const float* __restrict__ bnB,
    const float* __restrict__ vin, float* __restrict__ out) {
  __shared__ __align__(16) unsigned short lA[BM * BK];
  __shared__ __align__(16) unsigned short lB[BN * BK];
  const int flat = blockIdx.x;
  const int b = flat & 7;
  const int tile = flat >> 3;
  const int by = tile >> 3, bx = tile & 7;
  const int tid = threadIdx.x, lane = tid & 63, w = tid >> 6;
  const int wr = w >> 1, wc = w & 1;

  const unsigned short* Abase = M + ((size_t)b * 1024 + by * BM) * 512;
  const unsigned short* Bbase = thT + ((size_t)b * N_ + bx * BN) * 512;

  const int srow = w * 32 + (lane >> 3);
  const int sgl = lane & 7;

  f32x4 acc[4][4] = {};

  for (int kt = 0; kt < 512 / BK; ++kt) {
#pragma unroll
    for (int i = 0; i < 4; ++i) {
      const int r = srow + i * 8;
      const int gs = sgl ^ (r & 7);
      gload_lds16(Abase + (size_t)r * 512 + kt * BK + gs * 8,
                  (char*)lA + w * 4096 + i * 1024);
      gload_lds16(Bbase + (size_t)r * 512 + kt * BK + gs * 8,
                  (char*)lB + w * 4096 + i * 1024);
    }
    __syncthreads();
#pragma unroll
    for (int kk = 0; kk < 2; ++kk) {
      bf16x8 af[4], bfr[4];
#pragma unroll
      for (int mf = 0; mf < 4; ++mf) {
        const int r = wr * 64 + mf * 16 + (lane & 15);
        int byte = r * 128 + kk * 64 + ((lane >> 4) * 16);
        byte ^= (r & 7) << 4;
        af[mf] = *(const bf16x8*)((const char*)lA + byte);
      }
#pragma unroll
      for (int nf = 0; nf < 4; ++nf) {
        const int r = wc * 64 + nf * 16 + (lane & 15);
        int byte = r * 128 + kk * 64 + ((lane >> 4) * 16);
        byte ^= (r & 7) << 4;
        bfr[nf] = *(const bf16x8*)((const char*)lB + byte);
      }
#pragma unroll
      for (int mf = 0; mf < 4; ++mf)
#pragma unroll
        for (int nf = 0; nf < 4; ++nf)
          acc[mf][nf] = __builtin_amdgcn_mfma_f32_16x16x32_bf16(
              af[mf], bfr[nf], acc[mf][nf], 0, 0, 0);
    }
    __syncthreads();
  }

  const float icb = invC[b];
#pragma unroll
  for (int mf = 0; mf < 4; ++mf) {
#pragma unroll
    for (int nf = 0; nf < 4; ++nf) {
      const int col = bx * BN + wc * 64 + nf * 16 + (lane & 15);
      const int row0 = by * BM + wr * 64 + mf * 16 + ((lane >> 4) << 2);
      const float mv = mask[b * 1024 + col];
      const float sc = mv * icb;
#pragma unroll
      for (int r = 0; r < 4; ++r) {
        const int o = row0 + r;
        const float val = acc[mf][nf][r] * (sc * bnA[o]) + bnB[o];
        const size_t idx = ((size_t)b * 1024 + o) * 1024 + col;
        out[idx] = val * mv + vin[idx];
      }
    }
  }
}

extern "C" void kernel_launch(void* const* d_in, const int* in_sizes, int n_in,
                              void* d_out, int out_size, void* d_ws, size_t ws_size,
                              hipStream_t stream) {
  const float* v = (const float*)d_in[0];
  const float* mask = (const float*)d_in[1];
  const float* Wg = (const float*)d_in[2];
  const float* bg = (const float*)d_in[3];
  const float* Wt = (const float*)d_in[4];
  const float* bt = (const float*)d_in[5];
  const float* Wp = (const float*)d_in[6];
  const float* bp = (const float*)d_in[7];
  const float* Ww = (const float*)d_in[8];
  const float* bw = (const float*)d_in[9];
  const float* gamma = (const float*)d_in[10];
  const float* beta = (const float*)d_in[11];
  const float* mean = (const float*)d_in[12];
  const float* var = (const float*)d_in[13];
  float* out = (float*)d_out;

  char* ws = (char*)d_ws;
  unsigned short* vT = (unsigned short*)ws;    ws += 16777216;  // (b,n,d) bf16
  unsigned short* Wall = (unsigned short*)ws;  ws += 3145728;   // (1536,1024)
  unsigned short* Wwb = (unsigned short*)ws;   ws += 1048576;   // (1024,512)
  unsigned short* thT = (unsigned short*)ws;   ws += 8388608;   // (b,n,512)
  float* Spart = (float*)ws;                   ws += 4194304;   // (b,16,8,1024) f32
  unsigned short* Mw = (unsigned short*)ws;    ws += 8388608;   // (b,1024,512)
  float* ball = (float*)ws;                    ws += 6144;      // 1536
  float* invC = (float*)ws;                    ws += 32;        // 8
  float* bnA = (float*)ws;                     ws += 4096;      // 1024
  float* bnB = (float*)ws;                     ws += 4096;      // 1024

  k_prep<<<4105, 256, 0, stream>>>(v, Wt, Wp, Wg, Ww, bt, bp, bg, mask, bw,
                                   gamma, beta, mean, var, vT, Wall, Wwb, ball,
                                   invC, bnA, bnB);
  k_gemmA<<<768, 256, 0, stream>>>(Wall, vT, ball, mask, thT, Spart);
  k_M<<<dim3(8, 16, 8), 256, 0, stream>>>(Wwb, Spart, Mw);
  k_gemm2<<<512, 256, 0, stream>>>(Mw, thT, mask, invC, bnA, bnB, v, out);
}

// Round 6
// 164.794 us; speedup vs baseline: 1.0511x; 1.0149x over previous
//
#include <hip/hip_runtime.h>
#include <hip/hip_bf16.h>
#include <stdint.h>

// Problem constants
#define B_ 8
#define D_ 1024
#define N_ 1024
#define INTER_ 512
#define H_ 16
#define EPS_ 1e-5f

typedef __attribute__((ext_vector_type(8))) short bf16x8;
typedef __attribute__((ext_vector_type(4))) float f32x4;
typedef __attribute__((ext_vector_type(4))) unsigned short u16x4;
typedef __attribute__((ext_vector_type(8))) unsigned short u16x8;

__device__ __forceinline__ unsigned short f2bf(float f) {
  union { float f; uint32_t u; } v; v.f = f;
  uint32_t r = (v.u + 0x7FFFu + ((v.u >> 16) & 1u)) >> 16;  // RNE
  return (unsigned short)r;
}

__device__ __forceinline__ void gload_lds16(const void* g, void* l) {
  __builtin_amdgcn_global_load_lds(
      (const __attribute__((address_space(1))) void*)g,
      (__attribute__((address_space(3))) void*)l, 16, 0, 0);
}

// ---------------- fused prep: transpose-cast v | cast weights | small vecs
// blocks 0..2047: v transpose; 2048..4095: weight cast; 4096: biases+BN;
// 4097..4104: invC; 4105..4112: zero Sacc (for gemmA atomics)
__global__ __launch_bounds__(256) void k_prep(
    const float* __restrict__ v, const float* __restrict__ Wt,
    const float* __restrict__ Wp, const float* __restrict__ Wg,
    const float* __restrict__ Ww, const float* __restrict__ bt,
    const float* __restrict__ bp, const float* __restrict__ bg,
    const float* __restrict__ mask, const float* __restrict__ bw,
    const float* __restrict__ gamma, const float* __restrict__ beta,
    const float* __restrict__ mean, const float* __restrict__ var,
    unsigned short* __restrict__ vT, unsigned short* __restrict__ Wall,
    unsigned short* __restrict__ Wwb, float* __restrict__ ball,
    float* __restrict__ invC, float* __restrict__ bnA, float* __restrict__ bnB,
    float* __restrict__ Sacc) {
  const int blk = blockIdx.x, tid = threadIdx.x;
  if (blk < 2048) {
    __shared__ short T[64 * 72];
    const int b = blk >> 8, tile = blk & 255;
    const int n0 = (tile & 15) * 64, d0 = (tile >> 4) * 64;
    const float* src = v + ((size_t)b * D_ + d0) * N_ + n0;
    const int c = tid & 15, rg = tid >> 4;
#pragma unroll
    for (int i = 0; i < 4; ++i) {
      const int r = rg * 4 + i;
      float4 f = *(const float4*)(src + (size_t)r * N_ + c * 4);
      const int nl = c * 4;
      T[(nl + 0) * 72 + r] = f2bf(f.x);
      T[(nl + 1) * 72 + r] = f2bf(f.y);
      T[(nl + 2) * 72 + r] = f2bf(f.z);
      T[(nl + 3) * 72 + r] = f2bf(f.w);
    }
    __syncthreads();
    unsigned short* dst = vT + ((size_t)b * N_ + n0) * D_ + d0;
    const int ch = tid & 7, nr = tid >> 3;
#pragma unroll
    for (int jj = 0; jj < 2; ++jj) {
      const int nl = nr + jj * 32;
      u16x8 val = *(const u16x8*)&T[nl * 72 + ch * 8];
      *(u16x8*)(dst + (size_t)nl * D_ + ch * 8) = val;
    }
  } else if (blk < 4096) {
    const int idx4 = (blk - 2048) * 256 + tid;
    const int total1 = 1536 * 1024 / 4;
    if (idx4 < total1) {
      const int idx = idx4 * 4;
      const int row = idx >> 10, c = idx & 1023;
      const float* src = row < 512    ? Wt + row * 1024 + c
                         : row < 1024 ? Wp + (row - 512) * 1024 + c
                                      : Wg + (row - 1024) * 1024 + c;
      float4 f = *(const float4*)src;
      u16x4 o = {f2bf(f.x), f2bf(f.y), f2bf(f.z), f2bf(f.w)};
      *(u16x4*)(Wall + idx) = o;
    } else {
      const int idx = (idx4 - total1) * 4;
      float4 f = *(const float4*)(Ww + idx);
      u16x4 o = {f2bf(f.x), f2bf(f.y), f2bf(f.z), f2bf(f.w)};
      *(u16x4*)(Wwb + idx) = o;
    }
  } else if (blk == 4096) {
    for (int i = tid; i < 512; i += 256) {
      ball[i] = bt[i]; ball[512 + i] = bp[i]; ball[1024 + i] = bg[i];
    }
    for (int i = tid; i < 1024; i += 256) {
      const float inv = gamma[i] * rsqrtf(var[i] + EPS_);
      bnA[i] = inv;
      bnB[i] = (bw[i] - mean[i]) * inv + beta[i];
    }
  } else if (blk < 4105) {
    const int b = blk - 4097;
    float s = 0.f;
    for (int i = tid; i < 1024; i += 256) s += mask[b * 1024 + i];
    for (int off = 32; off; off >>= 1) s += __shfl_down(s, off, 64);
    __shared__ float red[4];
    if ((tid & 63) == 0) red[tid >> 6] = s;
    __syncthreads();
    if (tid == 0) invC[b] = 1.0f / (red[0] + red[1] + red[2] + red[3]);
  } else {
    // zero Sacc: 131072 floats total, 8 blocks x 16384 floats
    float4 z = {0.f, 0.f, 0.f, 0.f};
    float* dst = Sacc + (size_t)(blk - 4105) * 16384;
#pragma unroll
    for (int i = 0; i < 16; ++i)
      *(float4*)(dst + (size_t)(i * 256 + tid) * 4) = z;
  }
}

// ---------------- GEMM-A: theta -> thT | phi+g tiles -> S (atomic f32) -----
// flat grid 768: b = flat&7 (XCD-local batch), tile = flat>>3,
// by = tile>>3 (0..11), bx = tile&7 (bx fastest -> A-panel L2 reuse)
#define BM 128
#define BN 128
#define BK 64

__global__ __launch_bounds__(256, 3) void k_gemmA(
    const unsigned short* __restrict__ Wall, const unsigned short* __restrict__ vT,
    const float* __restrict__ ball, const float* __restrict__ mask,
    unsigned short* __restrict__ thT, float* __restrict__ Sacc) {
  __shared__ __align__(16) short smem[128 * 132];  // 33792 B
  char* lA = (char*)smem;
  char* lB = lA + 16384;
  const int flat = blockIdx.x;
  const int b = flat & 7;
  const int tile = flat >> 3;
  const int by = tile >> 3, bx = tile & 7;
  const int tid = threadIdx.x, lane = tid & 63, w = tid >> 6;
  const int wr = w >> 1, wc = w & 1;
  const bool is_theta = (by < 4);
  const int rg = by - 4;

  const unsigned short* Abase;
  if (is_theta)
    Abase = Wall + (size_t)(by * BM) * 1024;
  else
    Abase = (w < 2) ? Wall + (size_t)(512 + rg * 64) * 1024
                    : Wall + (size_t)(1024 + rg * 64 - 64) * 1024;
  const unsigned short* Bbase = vT + ((size_t)b * N_ + bx * BN) * 1024;

  const int srow = w * 32 + (lane >> 3);
  const int sgl = lane & 7;

  f32x4 acc[4][4] = {};

  for (int kt = 0; kt < 1024 / BK; ++kt) {
#pragma unroll
    for (int i = 0; i < 4; ++i) {
      const int r = srow + i * 8;
      const int gs = sgl ^ (r & 7);
      gload_lds16(Abase + (size_t)r * 1024 + kt * BK + gs * 8,
                  lA + w * 4096 + i * 1024);
      gload_lds16(Bbase + (size_t)r * 1024 + kt * BK + gs * 8,
                  lB + w * 4096 + i * 1024);
    }
    __syncthreads();
#pragma unroll
    for (int kk = 0; kk < 2; ++kk) {
      bf16x8 af[4], bfr[4];
#pragma unroll
      for (int mf = 0; mf < 4; ++mf) {
        const int r = wr * 64 + mf * 16 + (lane & 15);
        int byte = r * 128 + kk * 64 + ((lane >> 4) * 16);
        byte ^= (r & 7) << 4;
        af[mf] = *(const bf16x8*)(lA + byte);
      }
#pragma unroll
      for (int nf = 0; nf < 4; ++nf) {
        const int r = wc * 64 + nf * 16 + (lane & 15);
        int byte = r * 128 + kk * 64 + ((lane >> 4) * 16);
        byte ^= (r & 7) << 4;
        bfr[nf] = *(const bf16x8*)(lB + byte);
      }
#pragma unroll
      for (int mf = 0; mf < 4; ++mf)
#pragma unroll
        for (int nf = 0; nf < 4; ++nf)
          acc[mf][nf] = __builtin_amdgcn_mfma_f32_16x16x32_bf16(
              af[mf], bfr[nf], acc[mf][nf], 0, 0, 0);
    }
    __syncthreads();
  }

  short* Tc = smem;  // pitch 132 shorts
  if (is_theta) {
#pragma unroll
    for (int mf = 0; mf < 4; ++mf)
#pragma unroll
      for (int nf = 0; nf < 4; ++nf) {
        const int nl = wc * 64 + nf * 16 + (lane & 15);
        const int ol0 = wr * 64 + mf * 16 + ((lane >> 4) << 2);
        u16x4 o;
#pragma unroll
        for (int r = 0; r < 4; ++r)
          o[r] = f2bf(acc[mf][nf][r] + ball[by * BM + ol0 + r]);
        *(u16x4*)&Tc[nl * 132 + ol0] = o;
      }
    __syncthreads();
    const int ch = tid & 15;
#pragma unroll
    for (int j = 0; j < 8; ++j) {
      const int row = (tid >> 4) + j * 16;
      u16x4 lo = *(const u16x4*)&Tc[row * 132 + ch * 8];
      u16x4 hi = *(const u16x4*)&Tc[row * 132 + ch * 8 + 4];
      u16x8 val = {lo[0], lo[1], lo[2], lo[3], hi[0], hi[1], hi[2], hi[3]};
      *(u16x8*)(thT + ((size_t)b * N_ + bx * BN + row) * 512 + by * BM + ch * 8) =
          val;
    }
    return;
  }

  // ---- phi/g path: stage tiles to LDS (rows 0-63 phi, 64-127 g) ----
#pragma unroll
  for (int mf = 0; mf < 4; ++mf)
#pragma unroll
    for (int nf = 0; nf < 4; ++nf) {
      const int nl = wc * 64 + nf * 16 + (lane & 15);
      const int ol0 = wr * 64 + mf * 16 + ((lane >> 4) << 2);
      const float mv = (wr == 1) ? mask[b * 1024 + bx * BN + nl] : 1.0f;
      const int gb = (wr == 0) ? 512 + rg * 64 : 1024 + rg * 64 - 64;
#pragma unroll
      for (int r = 0; r < 4; ++r)
        Tc[(ol0 + r) * 132 + nl] =
            f2bf((acc[mf][nf][r] + ball[gb + ol0 + r]) * mv);
    }
  __syncthreads();

  // ---- S partials: per head hl (0,1), wave w = n-window w*32..+32 ----
  f32x4 accs[2][2][2] = {};
#pragma unroll
  for (int hl = 0; hl < 2; ++hl) {
    bf16x8 af[2], bfr[2];
#pragma unroll
    for (int mf = 0; mf < 2; ++mf) {
      const int row = hl * 32 + mf * 16 + (lane & 15);
      af[mf] = *(const bf16x8*)&Tc[row * 132 + w * 32 + (lane >> 4) * 8];
    }
#pragma unroll
    for (int nf = 0; nf < 2; ++nf) {
      const int row = 64 + hl * 32 + nf * 16 + (lane & 15);
      bfr[nf] = *(const bf16x8*)&Tc[row * 132 + w * 32 + (lane >> 4) * 8];
    }
#pragma unroll
    for (int mf = 0; mf < 2; ++mf)
#pragma unroll
      for (int nf = 0; nf < 2; ++nf)
        accs[hl][mf][nf] = __builtin_amdgcn_mfma_f32_16x16x32_bf16(
            af[mf], bfr[nf], accs[hl][mf][nf], 0, 0, 0);
  }
  __syncthreads();
  float* red = (float*)smem;  // [2][4][32][32] = 32 KB
#pragma unroll
  for (int hl = 0; hl < 2; ++hl)
#pragma unroll
    for (int mf = 0; mf < 2; ++mf)
#pragma unroll
      for (int nf = 0; nf < 2; ++nf)
#pragma unroll
        for (int r = 0; r < 4; ++r)
          red[((hl * 4 + w) * 32 + mf * 16 + (lane >> 4) * 4 + r) * 32 +
              nf * 16 + (lane & 15)] = accs[hl][mf][nf][r];
  __syncthreads();
  for (int e = tid; e < 2048; e += 256) {
    const int hl = e >> 10, idx = e & 1023;
    const float* rb = red + (hl * 4) * 1024;
    const float sum = rb[idx] + rb[1024 + idx] + rb[2048 + idx] + rb[3072 + idx];
    const int h = rg * 2 + hl;
    atomicAdd(&Sacc[((size_t)b * 16 + h) * 1024 + idx], sum);
  }
}

// ---------------- M[b](o, h*32+d) = sum_d' Ww[o,h*32+d'] * S[b,h,d,d'] -----
// flat grid 1024: b = flat&7 (XCD-aligned: Sacc read + Mw write stay in L2)
__global__ __launch_bounds__(256) void k_M(const unsigned short* __restrict__ Wwb,
                                           const float* __restrict__ Sacc,
                                           unsigned short* __restrict__ M) {
  const int flat = blockIdx.x;
  const int b = flat & 7;
  const int tile = flat >> 3;  // 0..127
  const int h = tile & 15, rb = tile >> 4;
  const int tid = threadIdx.x, lane = tid & 63, w = tid >> 6;
  __shared__ short Sb[32 * 40];
  {
    const int e0 = tid * 4;  // 256 threads x 4 floats = 1024
    float4 a = *(const float4*)(Sacc + (size_t)(b * 16 + h) * 1024 + e0);
    const int row = e0 >> 5, col = e0 & 31;
    u16x4 sv = {f2bf(a.x), f2bf(a.y), f2bf(a.z), f2bf(a.w)};
    *(u16x4*)&Sb[row * 40 + col] = sv;
  }
  __syncthreads();
  const int row0w = rb * 128 + w * 32;
  f32x4 acc[2][2] = {};
  bf16x8 af[2], bfr[2];
#pragma unroll
  for (int mf = 0; mf < 2; ++mf)
    af[mf] = *(const bf16x8*)(Wwb + (size_t)(row0w + mf * 16 + (lane & 15)) * 512 +
                              h * 32 + (lane >> 4) * 8);
#pragma unroll
  for (int nf = 0; nf < 2; ++nf)
    bfr[nf] = *(const bf16x8*)&Sb[(nf * 16 + (lane & 15)) * 40 + (lane >> 4) * 8];
#pragma unroll
  for (int mf = 0; mf < 2; ++mf)
#pragma unroll
    for (int nf = 0; nf < 2; ++nf)
      acc[mf][nf] = __builtin_amdgcn_mfma_f32_16x16x32_bf16(
          af[mf], bfr[nf], acc[mf][nf], 0, 0, 0);
#pragma unroll
  for (int mf = 0; mf < 2; ++mf)
#pragma unroll
    for (int nf = 0; nf < 2; ++nf)
#pragma unroll
      for (int r = 0; r < 4; ++r) {
        const int row = row0w + mf * 16 + (lane >> 4) * 4 + r;
        const int dp = nf * 16 + (lane & 15);
        M[((size_t)b * 1024 + row) * 512 + h * 32 + dp] = f2bf(acc[mf][nf][r]);
      }
}

// ---------------- GEMM2: out = (M*thT^T * sc)*bnA + bnB, *mask, + v --------
// flat grid 512: b = flat&7, tile = flat>>3, by = tile>>3, bx = tile&7
__global__ __launch_bounds__(256, 2) void k_gemm2(
    const unsigned short* __restrict__ M, const unsigned short* __restrict__ thT,
    const float* __restrict__ mask, const float* __restrict__ invC,
    const float* __restrict__ bnA, const float* __restrict__ bnB,
    const float* __restrict__ vin, float* __restrict__ out) {
  __shared__ __align__(16) unsigned short lA[BM * BK];
  __shared__ __align__(16) unsigned short lB[BN * BK];
  const int flat = blockIdx.x;
  const int b = flat & 7;
  const int tile = flat >> 3;
  const int by = tile >> 3, bx = tile & 7;
  const int tid = threadIdx.x, lane = tid & 63, w = tid >> 6;
  const int wr = w >> 1, wc = w & 1;

  const unsigned short* Abase = M + ((size_t)b * 1024 + by * BM) * 512;
  const unsigned short* Bbase = thT + ((size_t)b * N_ + bx * BN) * 512;

  const int srow = w * 32 + (lane >> 3);
  const int sgl = lane & 7;

  f32x4 acc[4][4] = {};

  for (int kt = 0; kt < 512 / BK; ++kt) {
#pragma unroll
    for (int i = 0; i < 4; ++i) {
      const int r = srow + i * 8;
      const int gs = sgl ^ (r & 7);
      gload_lds16(Abase + (size_t)r * 512 + kt * BK + gs * 8,
                  (char*)lA + w * 4096 + i * 1024);
      gload_lds16(Bbase + (size_t)r * 512 + kt * BK + gs * 8,
                  (char*)lB + w * 4096 + i * 1024);
    }
    __syncthreads();
#pragma unroll
    for (int kk = 0; kk < 2; ++kk) {
      bf16x8 af[4], bfr[4];
#pragma unroll
      for (int mf = 0; mf < 4; ++mf) {
        const int r = wr * 64 + mf * 16 + (lane & 15);
        int byte = r * 128 + kk * 64 + ((lane >> 4) * 16);
        byte ^= (r & 7) << 4;
        af[mf] = *(const bf16x8*)((const char*)lA + byte);
      }
#pragma unroll
      for (int nf = 0; nf < 4; ++nf) {
        const int r = wc * 64 + nf * 16 + (lane & 15);
        int byte = r * 128 + kk * 64 + ((lane >> 4) * 16);
        byte ^= (r & 7) << 4;
        bfr[nf] = *(const bf16x8*)((const char*)lB + byte);
      }
#pragma unroll
      for (int mf = 0; mf < 4; ++mf)
#pragma unroll
        for (int nf = 0; nf < 4; ++nf)
          acc[mf][nf] = __builtin_amdgcn_mfma_f32_16x16x32_bf16(
              af[mf], bfr[nf], acc[mf][nf], 0, 0, 0);
    }
    __syncthreads();
  }

  const float icb = invC[b];
#pragma unroll
  for (int mf = 0; mf < 4; ++mf) {
#pragma unroll
    for (int nf = 0; nf < 4; ++nf) {
      const int col = bx * BN + wc * 64 + nf * 16 + (lane & 15);
      const int row0 = by * BM + wr * 64 + mf * 16 + ((lane >> 4) << 2);
      const float mv = mask[b * 1024 + col];
      const float sc = mv * icb;
#pragma unroll
      for (int r = 0; r < 4; ++r) {
        const int o = row0 + r;
        const float val = acc[mf][nf][r] * (sc * bnA[o]) + bnB[o];
        const size_t idx = ((size_t)b * 1024 + o) * 1024 + col;
        out[idx] = val * mv + vin[idx];
      }
    }
  }
}

extern "C" void kernel_launch(void* const* d_in, const int* in_sizes, int n_in,
                              void* d_out, int out_size, void* d_ws, size_t ws_size,
                              hipStream_t stream) {
  const float* v = (const float*)d_in[0];
  const float* mask = (const float*)d_in[1];
  const float* Wg = (const float*)d_in[2];
  const float* bg = (const float*)d_in[3];
  const float* Wt = (const float*)d_in[4];
  const float* bt = (const float*)d_in[5];
  const float* Wp = (const float*)d_in[6];
  const float* bp = (const float*)d_in[7];
  const float* Ww = (const float*)d_in[8];
  const float* bw = (const float*)d_in[9];
  const float* gamma = (const float*)d_in[10];
  const float* beta = (const float*)d_in[11];
  const float* mean = (const float*)d_in[12];
  const float* var = (const float*)d_in[13];
  float* out = (float*)d_out;

  char* ws = (char*)d_ws;
  unsigned short* vT = (unsigned short*)ws;    ws += 16777216;  // (b,n,d) bf16
  unsigned short* Wall = (unsigned short*)ws;  ws += 3145728;   // (1536,1024)
  unsigned short* Wwb = (unsigned short*)ws;   ws += 1048576;   // (1024,512)
  unsigned short* thT = (unsigned short*)ws;   ws += 8388608;   // (b,n,512)
  float* Sacc = (float*)ws;                    ws += 524288;    // (b,16,1024) f32
  unsigned short* Mw = (unsigned short*)ws;    ws += 8388608;   // (b,1024,512)
  float* ball = (float*)ws;                    ws += 6144;      // 1536
  float* invC = (float*)ws;                    ws += 32;        // 8
  float* bnA = (float*)ws;                     ws += 4096;      // 1024
  float* bnB = (float*)ws;                     ws += 4096;      // 1024

  k_prep<<<4113, 256, 0, stream>>>(v, Wt, Wp, Wg, Ww, bt, bp, bg, mask, bw,
                                   gamma, beta, mean, var, vT, Wall, Wwb, ball,
                                   invC, bnA, bnB, Sacc);
  k_gemmA<<<768, 256, 0, stream>>>(Wall, vT, ball, mask, thT, Sacc);
  k_M<<<1024, 256, 0, stream>>>(Wwb, Sacc, Mw);
  k_gemm2<<<512, 256, 0, stream>>>(Mw, thT, mask, invC, bnA, bnB, v, out);
}